// Round 1
// baseline (1093.783 us; speedup 1.0000x reference)
//
#include <hip/hip_runtime.h>

#define N_NODES 50000
#define N_EDGES 800000
#define N_GRAPHS 64
#define F_IN 6
#define HID 64
#define EMB 128

// ---- init: deg = 1 (self loop), zero pool accumulators ----
__global__ void k_init(float* __restrict__ deg, float* __restrict__ gsum,
                       float* __restrict__ gcnt) {
    int i = blockIdx.x * blockDim.x + threadIdx.x;
    if (i < N_NODES) deg[i] = 1.0f;
    if (i < N_GRAPHS * HID) gsum[i] = 0.0f;
    if (i < N_GRAPHS) gcnt[i] = 0.0f;
}

// ---- degree count over edge destinations ----
__global__ void k_deg(const int* __restrict__ dst, float* __restrict__ deg) {
    int e = blockIdx.x * blockDim.x + threadIdx.x;
    if (e < N_EDGES) atomicAdd(&deg[dst[e]], 1.0f);
}

// ---- deg -> deg^{-1/2} in place ----
__global__ void k_dinv(float* __restrict__ deg) {
    int i = blockIdx.x * blockDim.x + threadIdx.x;
    if (i < N_NODES) deg[i] = rsqrtf(deg[i]);
}

// ---- h = x @ W ; acc = h * dinv^2 (self-loop contribution) ----
template <int IN>
__global__ void k_mm(const float* __restrict__ x, const float* __restrict__ W,
                     const float* __restrict__ dinv,
                     float* __restrict__ h, float* __restrict__ acc) {
    __shared__ float sW[IN * HID];
    for (int i = threadIdx.x; i < IN * HID; i += blockDim.x) sW[i] = W[i];
    __syncthreads();
    int gid = blockIdx.x * blockDim.x + threadIdx.x;
    int node = gid >> 6;          // 64 features per node
    int f = gid & 63;
    if (node >= N_NODES) return;
    float s = 0.0f;
#pragma unroll
    for (int k = 0; k < IN; ++k) s += x[node * IN + k] * sW[k * HID + f];
    h[node * HID + f] = s;
    float dv = dinv[node];
    acc[node * HID + f] = s * dv * dv;
}

// ---- edge scatter: acc[dst] += h[src] * dinv[src]*dinv[dst] ----
// one 64-lane wave = one edge; lane = feature -> coalesced gather + atomic
__global__ void k_scatter(const int* __restrict__ src, const int* __restrict__ dst,
                          const float* __restrict__ dinv,
                          const float* __restrict__ h, float* __restrict__ acc) {
    int gid = blockIdx.x * blockDim.x + threadIdx.x;
    int e = gid >> 6;
    int f = gid & 63;
    if (e >= N_EDGES) return;
    int s = src[e];
    int d = dst[e];
    float w = dinv[s] * dinv[d];
    atomicAdd(&acc[d * HID + f], h[s * HID + f] * w);
}

// ---- out = relu(acc + b) ----
__global__ void k_bias_relu(const float* __restrict__ acc, const float* __restrict__ b,
                            float* __restrict__ out) {
    int gid = blockIdx.x * blockDim.x + threadIdx.x;
    if (gid >= N_NODES * HID) return;
    out[gid] = fmaxf(acc[gid] + b[gid & 63], 0.0f);
}

// ---- segment sum for global mean pool ----
__global__ void k_pool(const float* __restrict__ x, const int* __restrict__ batch,
                       float* __restrict__ gsum, float* __restrict__ gcnt) {
    int gid = blockIdx.x * blockDim.x + threadIdx.x;
    if (gid >= N_NODES * HID) return;
    int node = gid >> 6;
    int f = gid & 63;
    int g = batch[node];
    atomicAdd(&gsum[g * HID + f], x[gid]);
    if (f == 0) atomicAdd(&gcnt[g], 1.0f);
}

// ---- final FC: out = relu((gsum/cnt) @ Wfc + bfc) ----
__global__ void k_fc(const float* __restrict__ gsum, const float* __restrict__ gcnt,
                     const float* __restrict__ Wfc, const float* __restrict__ bfc,
                     float* __restrict__ out) {
    int gid = blockIdx.x * blockDim.x + threadIdx.x;   // 64*128 threads
    if (gid >= N_GRAPHS * EMB) return;
    int g = gid >> 7;
    int j = gid & 127;
    float inv = 1.0f / fmaxf(gcnt[g], 1.0f);
    float s = bfc[j];
#pragma unroll 8
    for (int k = 0; k < HID; ++k) s += gsum[g * HID + k] * inv * Wfc[k * EMB + j];
    out[gid] = fmaxf(s, 0.0f);
}

extern "C" void kernel_launch(void* const* d_in, const int* in_sizes, int n_in,
                              void* d_out, int out_size, void* d_ws, size_t ws_size,
                              hipStream_t stream) {
    const float* x    = (const float*)d_in[0];
    const int*   ei   = (const int*)d_in[1];
    const int*   batch= (const int*)d_in[2];
    const float* W1   = (const float*)d_in[3];
    const float* b1   = (const float*)d_in[4];
    const float* W2   = (const float*)d_in[5];
    const float* b2   = (const float*)d_in[6];
    const float* W3   = (const float*)d_in[7];
    const float* b3   = (const float*)d_in[8];
    const float* Wfc  = (const float*)d_in[9];
    const float* bfc  = (const float*)d_in[10];
    float* out = (float*)d_out;

    float* ws   = (float*)d_ws;
    float* dinv = ws;                          // 50000 (deg, then dinv in place)
    float* h    = ws + 50048;                  // N*64
    float* acc  = h + N_NODES * HID;           // N*64
    float* xcur = acc + N_NODES * HID;         // N*64
    float* gsum = xcur + N_NODES * HID;        // 64*64
    float* gcnt = gsum + N_GRAPHS * HID;       // 64

    const int* src = ei;                       // edge_index[0]
    const int* dst = ei + N_EDGES;             // edge_index[1]

    const int B = 256;
    const int gN   = (N_NODES + B - 1) / B;
    const int gE   = (N_EDGES + B - 1) / B;
    const int gNF  = (N_NODES * HID + B - 1) / B;
    const int gEF  = (N_EDGES * HID + B - 1) / B;

    k_init<<<gN, B, 0, stream>>>(dinv, gsum, gcnt);
    k_deg<<<gE, B, 0, stream>>>(dst, dinv);
    k_dinv<<<gN, B, 0, stream>>>(dinv);

    // layer 1
    k_mm<F_IN><<<gNF, B, 0, stream>>>(x, W1, dinv, h, acc);
    k_scatter<<<gEF, B, 0, stream>>>(src, dst, dinv, h, acc);
    k_bias_relu<<<gNF, B, 0, stream>>>(acc, b1, xcur);
    // layer 2
    k_mm<HID><<<gNF, B, 0, stream>>>(xcur, W2, dinv, h, acc);
    k_scatter<<<gEF, B, 0, stream>>>(src, dst, dinv, h, acc);
    k_bias_relu<<<gNF, B, 0, stream>>>(acc, b2, xcur);
    // layer 3
    k_mm<HID><<<gNF, B, 0, stream>>>(xcur, W3, dinv, h, acc);
    k_scatter<<<gEF, B, 0, stream>>>(src, dst, dinv, h, acc);
    k_bias_relu<<<gNF, B, 0, stream>>>(acc, b3, xcur);

    // pool + FC
    k_pool<<<gNF, B, 0, stream>>>(xcur, batch, gsum, gcnt);
    k_fc<<<(N_GRAPHS * EMB + B - 1) / B, B, 0, stream>>>(gsum, gcnt, Wfc, bfc, out);
}

// Round 2
// 733.785 us; speedup vs baseline: 1.4906x; 1.4906x over previous
//
#include <hip/hip_runtime.h>

#define N_NODES 50000
#define N_EDGES 800000
#define N_GRAPHS 64
#define F_IN 6
#define HID 64
#define EMB 128

// ---- init: deg = 1 (self loop), zero pool accumulators ----
__global__ void k_init(float* __restrict__ deg, float* __restrict__ gsum,
                       float* __restrict__ gcnt) {
    int i = blockIdx.x * blockDim.x + threadIdx.x;
    if (i < N_NODES) deg[i] = 1.0f;
    if (i < N_GRAPHS * HID) gsum[i] = 0.0f;
    if (i < N_GRAPHS) gcnt[i] = 0.0f;
}

// ---- degree count over edge destinations ----
__global__ void k_deg(const int* __restrict__ dst, float* __restrict__ deg) {
    int e = blockIdx.x * blockDim.x + threadIdx.x;
    if (e < N_EDGES) atomicAdd(&deg[dst[e]], 1.0f);
}

// ---- deg -> deg^{-1/2} in place ----
__global__ void k_dinv(float* __restrict__ deg) {
    int i = blockIdx.x * blockDim.x + threadIdx.x;
    if (i < N_NODES) deg[i] = rsqrtf(deg[i]);
}

// ---- h = x @ W ; acc = h * dinv^2 (self-loop contribution) ----
template <int IN>
__global__ void k_mm(const float* __restrict__ x, const float* __restrict__ W,
                     const float* __restrict__ dinv,
                     float* __restrict__ h, float* __restrict__ acc) {
    __shared__ float sW[IN * HID];
    for (int i = threadIdx.x; i < IN * HID; i += blockDim.x) sW[i] = W[i];
    __syncthreads();
    int gid = blockIdx.x * blockDim.x + threadIdx.x;
    int node = gid >> 6;          // 64 features per node
    int f = gid & 63;
    if (node >= N_NODES) return;
    float s = 0.0f;
#pragma unroll
    for (int k = 0; k < IN; ++k) s += x[node * IN + k] * sW[k * HID + f];
    h[node * HID + f] = s;
    float dv = dinv[node];
    acc[node * HID + f] = s * dv * dv;
}

// ---- edge scatter: acc[dst] += h[src] * dinv[src]*dinv[dst] ----
// one 64-lane wave = one edge; lane = feature -> coalesced gather + atomic
__global__ void k_scatter(const int* __restrict__ src, const int* __restrict__ dst,
                          const float* __restrict__ dinv,
                          const float* __restrict__ h, float* __restrict__ acc) {
    int gid = blockIdx.x * blockDim.x + threadIdx.x;
    int e = gid >> 6;
    int f = gid & 63;
    if (e >= N_EDGES) return;
    int s = src[e];
    int d = dst[e];
    float w = dinv[s] * dinv[d];
    atomicAdd(&acc[d * HID + f], h[s * HID + f] * w);
}

// ---- out = relu(acc + b) ----
__global__ void k_bias_relu(const float* __restrict__ acc, const float* __restrict__ b,
                            float* __restrict__ out) {
    int gid = blockIdx.x * blockDim.x + threadIdx.x;
    if (gid >= N_NODES * HID) return;
    out[gid] = fmaxf(acc[gid] + b[gid & 63], 0.0f);
}

// ---- segment sum for global mean pool ----
// batch is SORTED: each block owns a contiguous node chunk; threads accumulate
// register partials per graph-id and flush one atomic per graph transition.
#define POOL_BLOCKS 200
__global__ void k_pool(const float* __restrict__ x, const int* __restrict__ batch,
                       float* __restrict__ gsum, float* __restrict__ gcnt) {
    const int npb = (N_NODES + POOL_BLOCKS - 1) / POOL_BLOCKS;   // 250
    int start = blockIdx.x * npb;
    int end = start + npb;
    if (end > N_NODES) end = N_NODES;
    int f = threadIdx.x & 63;
    int grp = threadIdx.x >> 6;       // 0..3 (4 waves)
    float sum = 0.0f, cnt = 0.0f;
    int curg = -1;
    for (int node = start + grp; node < end; node += 4) {
        int g = batch[node];
        if (g != curg) {
            if (curg >= 0) {
                atomicAdd(&gsum[curg * HID + f], sum);
                if (f == 0) atomicAdd(&gcnt[curg], cnt);
            }
            curg = g; sum = 0.0f; cnt = 0.0f;
        }
        sum += x[node * HID + f];
        cnt += 1.0f;
    }
    if (curg >= 0) {
        atomicAdd(&gsum[curg * HID + f], sum);
        if (f == 0) atomicAdd(&gcnt[curg], cnt);
    }
}

// ---- final FC: out = relu((gsum/cnt) @ Wfc + bfc) ----
__global__ void k_fc(const float* __restrict__ gsum, const float* __restrict__ gcnt,
                     const float* __restrict__ Wfc, const float* __restrict__ bfc,
                     float* __restrict__ out) {
    int gid = blockIdx.x * blockDim.x + threadIdx.x;   // 64*128 threads
    if (gid >= N_GRAPHS * EMB) return;
    int g = gid >> 7;
    int j = gid & 127;
    float inv = 1.0f / fmaxf(gcnt[g], 1.0f);
    float s = bfc[j];
#pragma unroll 8
    for (int k = 0; k < HID; ++k) s += gsum[g * HID + k] * inv * Wfc[k * EMB + j];
    out[gid] = fmaxf(s, 0.0f);
}

extern "C" void kernel_launch(void* const* d_in, const int* in_sizes, int n_in,
                              void* d_out, int out_size, void* d_ws, size_t ws_size,
                              hipStream_t stream) {
    const float* x    = (const float*)d_in[0];
    const int*   ei   = (const int*)d_in[1];
    const int*   batch= (const int*)d_in[2];
    const float* W1   = (const float*)d_in[3];
    const float* b1   = (const float*)d_in[4];
    const float* W2   = (const float*)d_in[5];
    const float* b2   = (const float*)d_in[6];
    const float* W3   = (const float*)d_in[7];
    const float* b3   = (const float*)d_in[8];
    const float* Wfc  = (const float*)d_in[9];
    const float* bfc  = (const float*)d_in[10];
    float* out = (float*)d_out;

    float* ws   = (float*)d_ws;
    float* dinv = ws;                          // 50000 (deg, then dinv in place)
    float* h    = ws + 50048;                  // N*64
    float* acc  = h + N_NODES * HID;           // N*64
    float* xcur = acc + N_NODES * HID;         // N*64
    float* gsum = xcur + N_NODES * HID;        // 64*64
    float* gcnt = gsum + N_GRAPHS * HID;       // 64

    const int* src = ei;                       // edge_index[0]
    const int* dst = ei + N_EDGES;             // edge_index[1]

    const int B = 256;
    const int gN   = (N_NODES + B - 1) / B;
    const int gE   = (N_EDGES + B - 1) / B;
    const int gNF  = (N_NODES * HID + B - 1) / B;
    const int gEF  = (N_EDGES * HID + B - 1) / B;

    k_init<<<gN, B, 0, stream>>>(dinv, gsum, gcnt);
    k_deg<<<gE, B, 0, stream>>>(dst, dinv);
    k_dinv<<<gN, B, 0, stream>>>(dinv);

    // layer 1
    k_mm<F_IN><<<gNF, B, 0, stream>>>(x, W1, dinv, h, acc);
    k_scatter<<<gEF, B, 0, stream>>>(src, dst, dinv, h, acc);
    k_bias_relu<<<gNF, B, 0, stream>>>(acc, b1, xcur);
    // layer 2
    k_mm<HID><<<gNF, B, 0, stream>>>(xcur, W2, dinv, h, acc);
    k_scatter<<<gEF, B, 0, stream>>>(src, dst, dinv, h, acc);
    k_bias_relu<<<gNF, B, 0, stream>>>(acc, b2, xcur);
    // layer 3
    k_mm<HID><<<gNF, B, 0, stream>>>(xcur, W3, dinv, h, acc);
    k_scatter<<<gEF, B, 0, stream>>>(src, dst, dinv, h, acc);
    k_bias_relu<<<gNF, B, 0, stream>>>(acc, b3, xcur);

    // pool + FC
    k_pool<<<POOL_BLOCKS, B, 0, stream>>>(xcur, batch, gsum, gcnt);
    k_fc<<<(N_GRAPHS * EMB + B - 1) / B, B, 0, stream>>>(gsum, gcnt, Wfc, bfc, out);
}

// Round 3
// 556.884 us; speedup vs baseline: 1.9641x; 1.3177x over previous
//
#include <hip/hip_runtime.h>

#define N_NODES 50000
#define N_EDGES 800000
#define N_GRAPHS 64
#define F_IN 6
#define HID 64
#define EMB 128

// ---- init: zero histogram + pool accumulators ----
__global__ void k_init(int* __restrict__ ecnt, float* __restrict__ gsum,
                       float* __restrict__ gcnt) {
    int i = blockIdx.x * blockDim.x + threadIdx.x;
    if (i < N_NODES) ecnt[i] = 0;
    if (i < N_GRAPHS * HID) gsum[i] = 0.0f;
    if (i < N_GRAPHS) gcnt[i] = 0.0f;
}

// ---- in-degree histogram over edge destinations ----
__global__ void k_hist(const int* __restrict__ dst, int* __restrict__ ecnt) {
    int e = blockIdx.x * blockDim.x + threadIdx.x;
    if (e < N_EDGES) atomicAdd(&ecnt[dst[e]], 1);
}

// ---- dinv = rsqrt(in_degree + 1)  (+1 = self-loop) ----
__global__ void k_dinv(const int* __restrict__ ecnt, float* __restrict__ dinv) {
    int i = blockIdx.x * blockDim.x + threadIdx.x;
    if (i < N_NODES) dinv[i] = rsqrtf((float)(ecnt[i] + 1));
}

// ---- single-block exclusive scan: ecnt -> row_start; zero pos ----
#define SCAN_T 1024
__global__ void k_scan(const int* __restrict__ ecnt, int* __restrict__ row_start,
                       int* __restrict__ pos) {
    __shared__ int part[SCAN_T];
    int t = threadIdx.x;
    const int per = (N_NODES + SCAN_T - 1) / SCAN_T;   // 49
    int lo = t * per;
    int hi = lo + per; if (hi > N_NODES) hi = N_NODES;
    int s = 0;
    for (int i = lo; i < hi; ++i) s += ecnt[i];
    part[t] = s;
    __syncthreads();
    for (int off = 1; off < SCAN_T; off <<= 1) {
        int other = (t >= off) ? part[t - off] : 0;
        __syncthreads();
        part[t] += other;
        __syncthreads();
    }
    int run = part[t] - s;          // exclusive prefix of this thread's chunk
    for (int i = lo; i < hi; ++i) {
        int c = ecnt[i];
        row_start[i] = run;
        run += c;
        pos[i] = 0;
    }
    if (t == SCAN_T - 1) row_start[N_NODES] = run;   // == N_EDGES
}

// ---- bucket edges by dst: epack[idx] = {src, w=dinv[src]*dinv[dst]} ----
__global__ void k_bucket(const int* __restrict__ src, const int* __restrict__ dst,
                         const float* __restrict__ dinv,
                         const int* __restrict__ row_start, int* __restrict__ pos,
                         int2* __restrict__ epack) {
    int e = blockIdx.x * blockDim.x + threadIdx.x;
    if (e >= N_EDGES) return;
    int s = src[e], d = dst[e];
    int p = atomicAdd(&pos[d], 1);
    float w = dinv[s] * dinv[d];
    epack[row_start[d] + p] = make_int2(s, __float_as_int(w));
}

// ---- h = x @ W ----
template <int IN>
__global__ void k_mm(const float* __restrict__ x, const float* __restrict__ W,
                     float* __restrict__ h) {
    __shared__ float sW[IN * HID];
    for (int i = threadIdx.x; i < IN * HID; i += blockDim.x) sW[i] = W[i];
    __syncthreads();
    int gid = blockIdx.x * blockDim.x + threadIdx.x;
    int node = gid >> 6;
    int f = gid & 63;
    if (node >= N_NODES) return;
    float s = 0.0f;
#pragma unroll
    for (int k = 0; k < IN; ++k) s += x[node * IN + k] * sW[k * HID + f];
    h[node * HID + f] = s;
}

// ---- per-node gather: out = relu(sum_in h[src]*w + h[node]*dinv^2 + b) ----
// one 64-lane wave per node; lane = feature
__global__ void k_gather(const float* __restrict__ h, const int* __restrict__ row_start,
                         const int2* __restrict__ epack, const float* __restrict__ dinv,
                         const float* __restrict__ b, float* __restrict__ out) {
    int node = (blockIdx.x * blockDim.x + threadIdx.x) >> 6;
    int f = threadIdx.x & 63;
    if (node >= N_NODES) return;
    int beg = row_start[node];
    int end = row_start[node + 1];
    float sum = 0.0f;
    for (int j = beg; j < end; ++j) {
        int2 p = epack[j];
        sum += h[p.x * HID + f] * __int_as_float(p.y);
    }
    float dv = dinv[node];
    sum += h[node * HID + f] * dv * dv;
    out[node * HID + f] = fmaxf(sum + b[f], 0.0f);
}

// ---- segment sum for global mean pool (batch sorted; register partials) ----
#define POOL_BLOCKS 200
__global__ void k_pool(const float* __restrict__ x, const int* __restrict__ batch,
                       float* __restrict__ gsum, float* __restrict__ gcnt) {
    const int npb = (N_NODES + POOL_BLOCKS - 1) / POOL_BLOCKS;   // 250
    int start = blockIdx.x * npb;
    int end = start + npb;
    if (end > N_NODES) end = N_NODES;
    int f = threadIdx.x & 63;
    int grp = threadIdx.x >> 6;       // 0..3 (4 waves)
    float sum = 0.0f, cnt = 0.0f;
    int curg = -1;
    for (int node = start + grp; node < end; node += 4) {
        int g = batch[node];
        if (g != curg) {
            if (curg >= 0) {
                atomicAdd(&gsum[curg * HID + f], sum);
                if (f == 0) atomicAdd(&gcnt[curg], cnt);
            }
            curg = g; sum = 0.0f; cnt = 0.0f;
        }
        sum += x[node * HID + f];
        cnt += 1.0f;
    }
    if (curg >= 0) {
        atomicAdd(&gsum[curg * HID + f], sum);
        if (f == 0) atomicAdd(&gcnt[curg], cnt);
    }
}

// ---- final FC: out = relu((gsum/cnt) @ Wfc + bfc) ----
__global__ void k_fc(const float* __restrict__ gsum, const float* __restrict__ gcnt,
                     const float* __restrict__ Wfc, const float* __restrict__ bfc,
                     float* __restrict__ out) {
    int gid = blockIdx.x * blockDim.x + threadIdx.x;   // 64*128 threads
    if (gid >= N_GRAPHS * EMB) return;
    int g = gid >> 7;
    int j = gid & 127;
    float inv = 1.0f / fmaxf(gcnt[g], 1.0f);
    float s = bfc[j];
#pragma unroll 8
    for (int k = 0; k < HID; ++k) s += gsum[g * HID + k] * inv * Wfc[k * EMB + j];
    out[gid] = fmaxf(s, 0.0f);
}

extern "C" void kernel_launch(void* const* d_in, const int* in_sizes, int n_in,
                              void* d_out, int out_size, void* d_ws, size_t ws_size,
                              hipStream_t stream) {
    const float* x    = (const float*)d_in[0];
    const int*   ei   = (const int*)d_in[1];
    const int*   batch= (const int*)d_in[2];
    const float* W1   = (const float*)d_in[3];
    const float* b1   = (const float*)d_in[4];
    const float* W2   = (const float*)d_in[5];
    const float* b2   = (const float*)d_in[6];
    const float* W3   = (const float*)d_in[7];
    const float* b3   = (const float*)d_in[8];
    const float* Wfc  = (const float*)d_in[9];
    const float* bfc  = (const float*)d_in[10];
    float* out = (float*)d_out;

    // workspace layout (4-byte words)
    float* ws        = (float*)d_ws;
    float* dinv      = ws;                                 // 50048
    float* h         = ws + 50048;                         // 3.2M
    float* xcur      = h + N_NODES * HID;                  // 3.2M
    float* gsum      = xcur + N_NODES * HID;               // 4096
    float* gcnt      = gsum + N_GRAPHS * HID;              // 64
    int*   ecnt      = (int*)(gcnt + 64);                  // 50048
    int*   row_start = ecnt + 50048;                       // 50056
    int*   pos       = row_start + 50056;                  // 50048
    int2*  epack     = (int2*)(pos + 50048);               // 800000 int2 (8B aligned)

    const int* src = ei;                       // edge_index[0]
    const int* dst = ei + N_EDGES;             // edge_index[1]

    const int B = 256;
    const int gN   = (N_NODES + B - 1) / B;
    const int gE   = (N_EDGES + B - 1) / B;
    const int gNF  = (N_NODES * HID + B - 1) / B;

    // CSR build
    k_init<<<gN, B, 0, stream>>>(ecnt, gsum, gcnt);
    k_hist<<<gE, B, 0, stream>>>(dst, ecnt);
    k_dinv<<<gN, B, 0, stream>>>(ecnt, dinv);
    k_scan<<<1, SCAN_T, 0, stream>>>(ecnt, row_start, pos);
    k_bucket<<<gE, B, 0, stream>>>(src, dst, dinv, row_start, pos, epack);

    // layer 1
    k_mm<F_IN><<<gNF, B, 0, stream>>>(x, W1, h);
    k_gather<<<gNF, B, 0, stream>>>(h, row_start, epack, dinv, b1, xcur);
    // layer 2
    k_mm<HID><<<gNF, B, 0, stream>>>(xcur, W2, h);
    k_gather<<<gNF, B, 0, stream>>>(h, row_start, epack, dinv, b2, xcur);
    // layer 3
    k_mm<HID><<<gNF, B, 0, stream>>>(xcur, W3, h);
    k_gather<<<gNF, B, 0, stream>>>(h, row_start, epack, dinv, b3, xcur);

    // pool + FC
    k_pool<<<POOL_BLOCKS, B, 0, stream>>>(xcur, batch, gsum, gcnt);
    k_fc<<<(N_GRAPHS * EMB + B - 1) / B, B, 0, stream>>>(gsum, gcnt, Wfc, bfc, out);
}

// Round 4
// 457.292 us; speedup vs baseline: 2.3919x; 1.2178x over previous
//
#include <hip/hip_runtime.h>

#define N_NODES 50000
#define N_EDGES 800000
#define N_GRAPHS 64
#define F_IN 6
#define HID 64
#define EMB 128

#define SCAN_B 256
#define NB_SCAN ((N_NODES + SCAN_B - 1) / SCAN_B)   // 196

// ---- init: zero histogram + pool accumulators ----
__global__ void k_init(int* __restrict__ ecnt, float* __restrict__ gsum,
                       float* __restrict__ gcnt) {
    int i = blockIdx.x * blockDim.x + threadIdx.x;
    if (i < N_NODES) ecnt[i] = 0;
    if (i < N_GRAPHS * HID) gsum[i] = 0.0f;
    if (i < N_GRAPHS) gcnt[i] = 0.0f;
}

// ---- in-degree histogram over edge destinations ----
__global__ void k_hist(const int* __restrict__ dst, int* __restrict__ ecnt) {
    int e = blockIdx.x * blockDim.x + threadIdx.x;
    if (e < N_EDGES) atomicAdd(&ecnt[dst[e]], 1);
}

// ---- pass 1: per-block sums of ecnt ----
__global__ void k_sum(const int* __restrict__ ecnt, int* __restrict__ bsum) {
    __shared__ int s[SCAN_B];
    int i = blockIdx.x * SCAN_B + threadIdx.x;
    s[threadIdx.x] = (i < N_NODES) ? ecnt[i] : 0;
    __syncthreads();
    for (int off = SCAN_B / 2; off > 0; off >>= 1) {
        if (threadIdx.x < off) s[threadIdx.x] += s[threadIdx.x + off];
        __syncthreads();
    }
    if (threadIdx.x == 0) bsum[blockIdx.x] = s[0];
}

// ---- pass 2: exclusive scan of the 196 block sums (one small block) ----
__global__ void k_bscan(const int* __restrict__ bsum, int* __restrict__ boff,
                        int* __restrict__ row_start) {
    __shared__ int s[SCAN_B];
    int t = threadIdx.x;
    int v = (t < NB_SCAN) ? bsum[t] : 0;
    s[t] = v;
    __syncthreads();
    for (int off = 1; off < SCAN_B; off <<= 1) {
        int other = (t >= off) ? s[t - off] : 0;
        __syncthreads();
        s[t] += other;
        __syncthreads();
    }
    if (t < NB_SCAN) boff[t] = s[t] - v;       // exclusive
    if (t == 0) row_start[N_NODES] = N_EDGES;  // known total
}

// ---- pass 3: per-chunk exclusive scan + offset; fused dinv; zero pos ----
__global__ void k_scan3(const int* __restrict__ ecnt, const int* __restrict__ boff,
                        int* __restrict__ row_start, int* __restrict__ pos,
                        float* __restrict__ dinv) {
    __shared__ int s[SCAN_B];
    int t = threadIdx.x;
    int i = blockIdx.x * SCAN_B + t;
    int v = (i < N_NODES) ? ecnt[i] : 0;
    s[t] = v;
    __syncthreads();
    for (int off = 1; off < SCAN_B; off <<= 1) {
        int other = (t >= off) ? s[t - off] : 0;
        __syncthreads();
        s[t] += other;
        __syncthreads();
    }
    if (i < N_NODES) {
        row_start[i] = boff[blockIdx.x] + s[t] - v;   // exclusive prefix
        pos[i] = 0;
        dinv[i] = rsqrtf((float)(v + 1));             // +1 = self-loop
    }
}

// ---- bucket edges by dst: epack[idx] = {src, w=dinv[src]*dinv[dst]} ----
__global__ void k_bucket(const int* __restrict__ src, const int* __restrict__ dst,
                         const float* __restrict__ dinv,
                         const int* __restrict__ row_start, int* __restrict__ pos,
                         int2* __restrict__ epack) {
    int e = blockIdx.x * blockDim.x + threadIdx.x;
    if (e >= N_EDGES) return;
    int s = src[e], d = dst[e];
    int p = atomicAdd(&pos[d], 1);
    float w = dinv[s] * dinv[d];
    epack[row_start[d] + p] = make_int2(s, __float_as_int(w));
}

// ---- h = x @ W ----
template <int IN>
__global__ void k_mm(const float* __restrict__ x, const float* __restrict__ W,
                     float* __restrict__ h) {
    __shared__ float sW[IN * HID];
    for (int i = threadIdx.x; i < IN * HID; i += blockDim.x) sW[i] = W[i];
    __syncthreads();
    int gid = blockIdx.x * blockDim.x + threadIdx.x;
    int node = gid >> 6;
    int f = gid & 63;
    if (node >= N_NODES) return;
    float s = 0.0f;
#pragma unroll
    for (int k = 0; k < IN; ++k) s += x[node * IN + k] * sW[k * HID + f];
    h[node * HID + f] = s;
}

// ---- per-node gather: out = relu(sum_in h[src]*w + h[node]*dinv^2 + b) ----
// one 64-lane wave per node; lane = feature
__global__ void k_gather(const float* __restrict__ h, const int* __restrict__ row_start,
                         const int2* __restrict__ epack, const float* __restrict__ dinv,
                         const float* __restrict__ b, float* __restrict__ out) {
    int node = (blockIdx.x * blockDim.x + threadIdx.x) >> 6;
    int f = threadIdx.x & 63;
    if (node >= N_NODES) return;
    int beg = row_start[node];
    int end = row_start[node + 1];
    float sum = 0.0f;
    for (int j = beg; j < end; ++j) {
        int2 p = epack[j];
        sum += h[p.x * HID + f] * __int_as_float(p.y);
    }
    float dv = dinv[node];
    sum += h[node * HID + f] * dv * dv;
    out[node * HID + f] = fmaxf(sum + b[f], 0.0f);
}

// ---- segment sum for global mean pool (batch sorted; register partials) ----
#define POOL_BLOCKS 200
__global__ void k_pool(const float* __restrict__ x, const int* __restrict__ batch,
                       float* __restrict__ gsum, float* __restrict__ gcnt) {
    const int npb = (N_NODES + POOL_BLOCKS - 1) / POOL_BLOCKS;   // 250
    int start = blockIdx.x * npb;
    int end = start + npb;
    if (end > N_NODES) end = N_NODES;
    int f = threadIdx.x & 63;
    int grp = threadIdx.x >> 6;       // 0..3 (4 waves)
    float sum = 0.0f, cnt = 0.0f;
    int curg = -1;
    for (int node = start + grp; node < end; node += 4) {
        int g = batch[node];
        if (g != curg) {
            if (curg >= 0) {
                atomicAdd(&gsum[curg * HID + f], sum);
                if (f == 0) atomicAdd(&gcnt[curg], cnt);
            }
            curg = g; sum = 0.0f; cnt = 0.0f;
        }
        sum += x[node * HID + f];
        cnt += 1.0f;
    }
    if (curg >= 0) {
        atomicAdd(&gsum[curg * HID + f], sum);
        if (f == 0) atomicAdd(&gcnt[curg], cnt);
    }
}

// ---- final FC: out = relu((gsum/cnt) @ Wfc + bfc) ----
__global__ void k_fc(const float* __restrict__ gsum, const float* __restrict__ gcnt,
                     const float* __restrict__ Wfc, const float* __restrict__ bfc,
                     float* __restrict__ out) {
    int gid = blockIdx.x * blockDim.x + threadIdx.x;   // 64*128 threads
    if (gid >= N_GRAPHS * EMB) return;
    int g = gid >> 7;
    int j = gid & 127;
    float inv = 1.0f / fmaxf(gcnt[g], 1.0f);
    float s = bfc[j];
#pragma unroll 8
    for (int k = 0; k < HID; ++k) s += gsum[g * HID + k] * inv * Wfc[k * EMB + j];
    out[gid] = fmaxf(s, 0.0f);
}

extern "C" void kernel_launch(void* const* d_in, const int* in_sizes, int n_in,
                              void* d_out, int out_size, void* d_ws, size_t ws_size,
                              hipStream_t stream) {
    const float* x    = (const float*)d_in[0];
    const int*   ei   = (const int*)d_in[1];
    const int*   batch= (const int*)d_in[2];
    const float* W1   = (const float*)d_in[3];
    const float* b1   = (const float*)d_in[4];
    const float* W2   = (const float*)d_in[5];
    const float* b2   = (const float*)d_in[6];
    const float* W3   = (const float*)d_in[7];
    const float* b3   = (const float*)d_in[8];
    const float* Wfc  = (const float*)d_in[9];
    const float* bfc  = (const float*)d_in[10];
    float* out = (float*)d_out;

    // workspace layout (4-byte words)
    float* ws        = (float*)d_ws;
    float* dinv      = ws;                                 // 50048
    float* h         = ws + 50048;                         // 3.2M
    float* xcur      = h + N_NODES * HID;                  // 3.2M
    float* gsum      = xcur + N_NODES * HID;               // 4096
    float* gcnt      = gsum + N_GRAPHS * HID;              // 64
    int*   ecnt      = (int*)(gcnt + 64);                  // 50048
    int*   row_start = ecnt + 50048;                       // 50056
    int*   pos       = row_start + 50056;                  // 50048
    int*   bsum      = pos + 50048;                        // 256
    int*   boff      = bsum + 256;                         // 256
    int2*  epack     = (int2*)(boff + 256);                // 800000 int2 (8B aligned)

    const int* src = ei;                       // edge_index[0]
    const int* dst = ei + N_EDGES;             // edge_index[1]

    const int B = 256;
    const int gN   = (N_NODES + B - 1) / B;
    const int gE   = (N_EDGES + B - 1) / B;
    const int gNF  = (N_NODES * HID + B - 1) / B;

    // CSR build
    k_init<<<gN, B, 0, stream>>>(ecnt, gsum, gcnt);
    k_hist<<<gE, B, 0, stream>>>(dst, ecnt);
    k_sum<<<NB_SCAN, SCAN_B, 0, stream>>>(ecnt, bsum);
    k_bscan<<<1, SCAN_B, 0, stream>>>(bsum, boff, row_start);
    k_scan3<<<NB_SCAN, SCAN_B, 0, stream>>>(ecnt, boff, row_start, pos, dinv);
    k_bucket<<<gE, B, 0, stream>>>(src, dst, dinv, row_start, pos, epack);

    // layer 1
    k_mm<F_IN><<<gNF, B, 0, stream>>>(x, W1, h);
    k_gather<<<gNF, B, 0, stream>>>(h, row_start, epack, dinv, b1, xcur);
    // layer 2
    k_mm<HID><<<gNF, B, 0, stream>>>(xcur, W2, h);
    k_gather<<<gNF, B, 0, stream>>>(h, row_start, epack, dinv, b2, xcur);
    // layer 3
    k_mm<HID><<<gNF, B, 0, stream>>>(xcur, W3, h);
    k_gather<<<gNF, B, 0, stream>>>(h, row_start, epack, dinv, b3, xcur);

    // pool + FC
    k_pool<<<POOL_BLOCKS, B, 0, stream>>>(xcur, batch, gsum, gcnt);
    k_fc<<<(N_GRAPHS * EMB + B - 1) / B, B, 0, stream>>>(gsum, gcnt, Wfc, bfc, out);
}

// Round 5
// 307.430 us; speedup vs baseline: 3.5578x; 1.4875x over previous
//
#include <hip/hip_runtime.h>

#define N_NODES 50000
#define N_EDGES 800000
#define N_GRAPHS 64
#define F_IN 6
#define HID 64
#define EMB 128

#define SCAN_B 256
#define NB_SCAN ((N_NODES + SCAN_B - 1) / SCAN_B)   // 196

// ---- init: zero histogram + pool accumulators ----
__global__ void k_init(int* __restrict__ ecnt, float* __restrict__ gsum,
                       float* __restrict__ gcnt) {
    int i = blockIdx.x * blockDim.x + threadIdx.x;
    if (i < N_NODES) ecnt[i] = 0;
    if (i < N_GRAPHS * HID) gsum[i] = 0.0f;
    if (i < N_GRAPHS) gcnt[i] = 0.0f;
}

// ---- in-degree histogram over edge destinations ----
__global__ void k_hist(const int* __restrict__ dst, int* __restrict__ ecnt) {
    int e = blockIdx.x * blockDim.x + threadIdx.x;
    if (e < N_EDGES) atomicAdd(&ecnt[dst[e]], 1);
}

// ---- pass 1: per-block sums of ecnt ----
__global__ void k_sum(const int* __restrict__ ecnt, int* __restrict__ bsum) {
    __shared__ int s[SCAN_B];
    int i = blockIdx.x * SCAN_B + threadIdx.x;
    s[threadIdx.x] = (i < N_NODES) ? ecnt[i] : 0;
    __syncthreads();
    for (int off = SCAN_B / 2; off > 0; off >>= 1) {
        if (threadIdx.x < off) s[threadIdx.x] += s[threadIdx.x + off];
        __syncthreads();
    }
    if (threadIdx.x == 0) bsum[blockIdx.x] = s[0];
}

// ---- pass 2: exclusive scan of the 196 block sums (one small block) ----
__global__ void k_bscan(const int* __restrict__ bsum, int* __restrict__ boff,
                        int* __restrict__ row_start) {
    __shared__ int s[SCAN_B];
    int t = threadIdx.x;
    int v = (t < NB_SCAN) ? bsum[t] : 0;
    s[t] = v;
    __syncthreads();
    for (int off = 1; off < SCAN_B; off <<= 1) {
        int other = (t >= off) ? s[t - off] : 0;
        __syncthreads();
        s[t] += other;
        __syncthreads();
    }
    if (t < NB_SCAN) boff[t] = s[t] - v;       // exclusive
    if (t == 0) row_start[N_NODES] = N_EDGES;  // known total
}

// ---- pass 3: per-chunk exclusive scan + offset; fused dinv; zero pos ----
__global__ void k_scan3(const int* __restrict__ ecnt, const int* __restrict__ boff,
                        int* __restrict__ row_start, int* __restrict__ pos,
                        float* __restrict__ dinv) {
    __shared__ int s[SCAN_B];
    int t = threadIdx.x;
    int i = blockIdx.x * SCAN_B + t;
    int v = (i < N_NODES) ? ecnt[i] : 0;
    s[t] = v;
    __syncthreads();
    for (int off = 1; off < SCAN_B; off <<= 1) {
        int other = (t >= off) ? s[t - off] : 0;
        __syncthreads();
        s[t] += other;
        __syncthreads();
    }
    if (i < N_NODES) {
        row_start[i] = boff[blockIdx.x] + s[t] - v;   // exclusive prefix
        pos[i] = 0;
        dinv[i] = rsqrtf((float)(v + 1));             // +1 = self-loop
    }
}

// ---- bucket edges by dst: epack[idx] = {src, w=dinv[src]*dinv[dst]} ----
__global__ void k_bucket(const int* __restrict__ src, const int* __restrict__ dst,
                         const float* __restrict__ dinv,
                         const int* __restrict__ row_start, int* __restrict__ pos,
                         int2* __restrict__ epack) {
    int e = blockIdx.x * blockDim.x + threadIdx.x;
    if (e >= N_EDGES) return;
    int s = src[e], d = dst[e];
    int p = atomicAdd(&pos[d], 1);
    float w = dinv[s] * dinv[d];
    epack[row_start[d] + p] = make_int2(s, __float_as_int(w));
}

// ---- layer-1 aggregation on raw x (6 features): xagg = A_hat @ x ----
// one 64-lane wave per node; lanes 0..5 hold features, all lanes see epack
__global__ void k_gather_x(const float* __restrict__ x, const int* __restrict__ row_start,
                           const int2* __restrict__ epack, const float* __restrict__ dinv,
                           float* __restrict__ xagg) {
    int node = (blockIdx.x * blockDim.x + threadIdx.x) >> 6;
    int f = threadIdx.x & 63;
    if (node >= N_NODES) return;
    int beg = __builtin_amdgcn_readfirstlane(row_start[node]);
    int end = __builtin_amdgcn_readfirstlane(row_start[node + 1]);
    bool act = (f < F_IN);
    float sum = 0.0f;
    int j = beg;
    for (; j + 8 <= end; j += 8) {
        int2 p0 = epack[j+0]; int2 p1 = epack[j+1];
        int2 p2 = epack[j+2]; int2 p3 = epack[j+3];
        int2 p4 = epack[j+4]; int2 p5 = epack[j+5];
        int2 p6 = epack[j+6]; int2 p7 = epack[j+7];
        if (act) {
            float v0 = x[p0.x * F_IN + f], v1 = x[p1.x * F_IN + f];
            float v2 = x[p2.x * F_IN + f], v3 = x[p3.x * F_IN + f];
            float v4 = x[p4.x * F_IN + f], v5 = x[p5.x * F_IN + f];
            float v6 = x[p6.x * F_IN + f], v7 = x[p7.x * F_IN + f];
            sum += v0 * __int_as_float(p0.y) + v1 * __int_as_float(p1.y)
                 + v2 * __int_as_float(p2.y) + v3 * __int_as_float(p3.y)
                 + v4 * __int_as_float(p4.y) + v5 * __int_as_float(p5.y)
                 + v6 * __int_as_float(p6.y) + v7 * __int_as_float(p7.y);
        }
    }
    for (; j < end; ++j) {
        int2 p = epack[j];
        if (act) sum += x[p.x * F_IN + f] * __int_as_float(p.y);
    }
    if (act) {
        float dv = dinv[node];
        sum += x[node * F_IN + f] * dv * dv;
        xagg[node * F_IN + f] = sum;
    }
}

// ---- layer-1 matmul fused with bias+relu: out = relu(xagg @ W + b) ----
__global__ void k_mm_br(const float* __restrict__ xagg, const float* __restrict__ W,
                        const float* __restrict__ b, float* __restrict__ out) {
    __shared__ float sW[F_IN * HID];
    for (int i = threadIdx.x; i < F_IN * HID; i += blockDim.x) sW[i] = W[i];
    __syncthreads();
    int gid = blockIdx.x * blockDim.x + threadIdx.x;
    int node = gid >> 6;
    int f = gid & 63;
    if (node >= N_NODES) return;
    float s = b[f];
#pragma unroll
    for (int k = 0; k < F_IN; ++k) s += xagg[node * F_IN + k] * sW[k * HID + f];
    out[node * HID + f] = fmaxf(s, 0.0f);
}

// ---- h = x @ W (64-wide) ----
__global__ void k_mm(const float* __restrict__ x, const float* __restrict__ W,
                     float* __restrict__ h) {
    __shared__ float sW[HID * HID];
    for (int i = threadIdx.x; i < HID * HID; i += blockDim.x) sW[i] = W[i];
    __syncthreads();
    int gid = blockIdx.x * blockDim.x + threadIdx.x;
    int node = gid >> 6;
    int f = gid & 63;
    if (node >= N_NODES) return;
    float s = 0.0f;
#pragma unroll
    for (int k = 0; k < HID; ++k) s += x[node * HID + k] * sW[k * HID + f];
    h[node * HID + f] = s;
}

// ---- per-node gather (64 features), 8x unrolled for ILP ----
__global__ void k_gather(const float* __restrict__ h, const int* __restrict__ row_start,
                         const int2* __restrict__ epack, const float* __restrict__ dinv,
                         const float* __restrict__ b, float* __restrict__ out) {
    int node = (blockIdx.x * blockDim.x + threadIdx.x) >> 6;
    int f = threadIdx.x & 63;
    if (node >= N_NODES) return;
    int beg = __builtin_amdgcn_readfirstlane(row_start[node]);
    int end = __builtin_amdgcn_readfirstlane(row_start[node + 1]);
    float sum = 0.0f;
    int j = beg;
    for (; j + 8 <= end; j += 8) {
        int2 p0 = epack[j+0]; int2 p1 = epack[j+1];
        int2 p2 = epack[j+2]; int2 p3 = epack[j+3];
        int2 p4 = epack[j+4]; int2 p5 = epack[j+5];
        int2 p6 = epack[j+6]; int2 p7 = epack[j+7];
        float v0 = h[p0.x * HID + f], v1 = h[p1.x * HID + f];
        float v2 = h[p2.x * HID + f], v3 = h[p3.x * HID + f];
        float v4 = h[p4.x * HID + f], v5 = h[p5.x * HID + f];
        float v6 = h[p6.x * HID + f], v7 = h[p7.x * HID + f];
        sum += v0 * __int_as_float(p0.y) + v1 * __int_as_float(p1.y)
             + v2 * __int_as_float(p2.y) + v3 * __int_as_float(p3.y)
             + v4 * __int_as_float(p4.y) + v5 * __int_as_float(p5.y)
             + v6 * __int_as_float(p6.y) + v7 * __int_as_float(p7.y);
    }
    for (; j < end; ++j) {
        int2 p = epack[j];
        sum += h[p.x * HID + f] * __int_as_float(p.y);
    }
    float dv = dinv[node];
    sum += h[node * HID + f] * dv * dv;
    out[node * HID + f] = fmaxf(sum + b[f], 0.0f);
}

// ---- segment sum for global mean pool (batch sorted; register partials) ----
#define POOL_BLOCKS 200
__global__ void k_pool(const float* __restrict__ x, const int* __restrict__ batch,
                       float* __restrict__ gsum, float* __restrict__ gcnt) {
    const int npb = (N_NODES + POOL_BLOCKS - 1) / POOL_BLOCKS;   // 250
    int start = blockIdx.x * npb;
    int end = start + npb;
    if (end > N_NODES) end = N_NODES;
    int f = threadIdx.x & 63;
    int grp = threadIdx.x >> 6;       // 0..3 (4 waves)
    float sum = 0.0f, cnt = 0.0f;
    int curg = -1;
    for (int node = start + grp; node < end; node += 4) {
        int g = batch[node];
        if (g != curg) {
            if (curg >= 0) {
                atomicAdd(&gsum[curg * HID + f], sum);
                if (f == 0) atomicAdd(&gcnt[curg], cnt);
            }
            curg = g; sum = 0.0f; cnt = 0.0f;
        }
        sum += x[node * HID + f];
        cnt += 1.0f;
    }
    if (curg >= 0) {
        atomicAdd(&gsum[curg * HID + f], sum);
        if (f == 0) atomicAdd(&gcnt[curg], cnt);
    }
}

// ---- final FC: out = relu((gsum/cnt) @ Wfc + bfc) ----
__global__ void k_fc(const float* __restrict__ gsum, const float* __restrict__ gcnt,
                     const float* __restrict__ Wfc, const float* __restrict__ bfc,
                     float* __restrict__ out) {
    int gid = blockIdx.x * blockDim.x + threadIdx.x;   // 64*128 threads
    if (gid >= N_GRAPHS * EMB) return;
    int g = gid >> 7;
    int j = gid & 127;
    float inv = 1.0f / fmaxf(gcnt[g], 1.0f);
    float s = bfc[j];
#pragma unroll 8
    for (int k = 0; k < HID; ++k) s += gsum[g * HID + k] * inv * Wfc[k * EMB + j];
    out[gid] = fmaxf(s, 0.0f);
}

extern "C" void kernel_launch(void* const* d_in, const int* in_sizes, int n_in,
                              void* d_out, int out_size, void* d_ws, size_t ws_size,
                              hipStream_t stream) {
    const float* x    = (const float*)d_in[0];
    const int*   ei   = (const int*)d_in[1];
    const int*   batch= (const int*)d_in[2];
    const float* W1   = (const float*)d_in[3];
    const float* b1   = (const float*)d_in[4];
    const float* W2   = (const float*)d_in[5];
    const float* b2   = (const float*)d_in[6];
    const float* W3   = (const float*)d_in[7];
    const float* b3   = (const float*)d_in[8];
    const float* Wfc  = (const float*)d_in[9];
    const float* bfc  = (const float*)d_in[10];
    float* out = (float*)d_out;

    // workspace layout (4-byte words)
    float* ws        = (float*)d_ws;
    float* dinv      = ws;                                 // 50048
    float* h         = ws + 50048;                         // 3.2M (also xagg in layer 1)
    float* xcur      = h + N_NODES * HID;                  // 3.2M
    float* gsum      = xcur + N_NODES * HID;               // 4096
    float* gcnt      = gsum + N_GRAPHS * HID;               // 64
    int*   ecnt      = (int*)(gcnt + 64);                  // 50048
    int*   row_start = ecnt + 50048;                       // 50056
    int*   pos       = row_start + 50056;                  // 50048
    int*   bsum      = pos + 50048;                        // 256
    int*   boff      = bsum + 256;                         // 256
    int2*  epack     = (int2*)(boff + 256);                // 800000 int2 (8B aligned)
    float* xagg      = h;                                  // [N, F_IN] reuse (h dead in layer 1)

    const int* src = ei;                       // edge_index[0]
    const int* dst = ei + N_EDGES;             // edge_index[1]

    const int B = 256;
    const int gN   = (N_NODES + B - 1) / B;
    const int gE   = (N_EDGES + B - 1) / B;
    const int gNF  = (N_NODES * HID + B - 1) / B;

    // CSR build
    k_init<<<gN, B, 0, stream>>>(ecnt, gsum, gcnt);
    k_hist<<<gE, B, 0, stream>>>(dst, ecnt);
    k_sum<<<NB_SCAN, SCAN_B, 0, stream>>>(ecnt, bsum);
    k_bscan<<<1, SCAN_B, 0, stream>>>(bsum, boff, row_start);
    k_scan3<<<NB_SCAN, SCAN_B, 0, stream>>>(ecnt, boff, row_start, pos, dinv);
    k_bucket<<<gE, B, 0, stream>>>(src, dst, dinv, row_start, pos, epack);

    // layer 1: aggregate-then-transform (X is only 6-wide)
    k_gather_x<<<gNF, B, 0, stream>>>(x, row_start, epack, dinv, xagg);
    k_mm_br<<<gNF, B, 0, stream>>>(xagg, W1, b1, xcur);
    // layer 2
    k_mm<<<gNF, B, 0, stream>>>(xcur, W2, h);
    k_gather<<<gNF, B, 0, stream>>>(h, row_start, epack, dinv, b2, xcur);
    // layer 3
    k_mm<<<gNF, B, 0, stream>>>(xcur, W3, h);
    k_gather<<<gNF, B, 0, stream>>>(h, row_start, epack, dinv, b3, xcur);

    // pool + FC
    k_pool<<<POOL_BLOCKS, B, 0, stream>>>(xcur, batch, gsum, gcnt);
    k_fc<<<(N_GRAPHS * EMB + B - 1) / B, B, 0, stream>>>(gsum, gcnt, Wfc, bfc, out);
}

// Round 6
// 259.162 us; speedup vs baseline: 4.2205x; 1.1862x over previous
//
#include <hip/hip_runtime.h>

#define N_NODES 50000
#define N_EDGES 800000
#define N_GRAPHS 64
#define F_IN 6
#define HID 64
#define EMB 128

#define SCAN_B 256
#define NB_SCAN ((N_NODES + SCAN_B - 1) / SCAN_B)   // 196

// ---- init: zero histogram + pool accumulators ----
__global__ void k_init(int* __restrict__ ecnt, float* __restrict__ gsum,
                       float* __restrict__ gcnt) {
    int i = blockIdx.x * blockDim.x + threadIdx.x;
    if (i < N_NODES) ecnt[i] = 0;
    if (i < N_GRAPHS * HID) gsum[i] = 0.0f;
    if (i < N_GRAPHS) gcnt[i] = 0.0f;
}

// ---- in-degree histogram over edge destinations ----
__global__ void k_hist(const int* __restrict__ dst, int* __restrict__ ecnt) {
    int e = blockIdx.x * blockDim.x + threadIdx.x;
    if (e < N_EDGES) atomicAdd(&ecnt[dst[e]], 1);
}

// ---- pass 1: per-block sums of ecnt ----
__global__ void k_sum(const int* __restrict__ ecnt, int* __restrict__ bsum) {
    __shared__ int s[SCAN_B];
    int i = blockIdx.x * SCAN_B + threadIdx.x;
    s[threadIdx.x] = (i < N_NODES) ? ecnt[i] : 0;
    __syncthreads();
    for (int off = SCAN_B / 2; off > 0; off >>= 1) {
        if (threadIdx.x < off) s[threadIdx.x] += s[threadIdx.x + off];
        __syncthreads();
    }
    if (threadIdx.x == 0) bsum[blockIdx.x] = s[0];
}

// ---- pass 2: exclusive scan of the 196 block sums (one small block) ----
__global__ void k_bscan(const int* __restrict__ bsum, int* __restrict__ boff,
                        int* __restrict__ row_start) {
    __shared__ int s[SCAN_B];
    int t = threadIdx.x;
    int v = (t < NB_SCAN) ? bsum[t] : 0;
    s[t] = v;
    __syncthreads();
    for (int off = 1; off < SCAN_B; off <<= 1) {
        int other = (t >= off) ? s[t - off] : 0;
        __syncthreads();
        s[t] += other;
        __syncthreads();
    }
    if (t < NB_SCAN) boff[t] = s[t] - v;       // exclusive
    if (t == 0) row_start[N_NODES] = N_EDGES;  // known total
}

// ---- pass 3: per-chunk exclusive scan + offset; fused dinv; zero pos ----
__global__ void k_scan3(const int* __restrict__ ecnt, const int* __restrict__ boff,
                        int* __restrict__ row_start, int* __restrict__ pos,
                        float* __restrict__ dinv) {
    __shared__ int s[SCAN_B];
    int t = threadIdx.x;
    int i = blockIdx.x * SCAN_B + t;
    int v = (i < N_NODES) ? ecnt[i] : 0;
    s[t] = v;
    __syncthreads();
    for (int off = 1; off < SCAN_B; off <<= 1) {
        int other = (t >= off) ? s[t - off] : 0;
        __syncthreads();
        s[t] += other;
        __syncthreads();
    }
    if (i < N_NODES) {
        row_start[i] = boff[blockIdx.x] + s[t] - v;   // exclusive prefix
        pos[i] = 0;
        dinv[i] = rsqrtf((float)(v + 1));             // +1 = self-loop
    }
}

// ---- bucket edges by dst: epack[idx] = {src, w=dinv[src]*dinv[dst]} ----
__global__ void k_bucket(const int* __restrict__ src, const int* __restrict__ dst,
                         const float* __restrict__ dinv,
                         const int* __restrict__ row_start, int* __restrict__ pos,
                         int2* __restrict__ epack) {
    int e = blockIdx.x * blockDim.x + threadIdx.x;
    if (e >= N_EDGES) return;
    int s = src[e], d = dst[e];
    int p = atomicAdd(&pos[d], 1);
    float w = dinv[s] * dinv[d];
    epack[row_start[d] + p] = make_int2(s, __float_as_int(w));
}

// ---- layer-1 aggregation on raw x (6 features): xagg = A_hat @ x ----
__global__ void k_gather_x(const float* __restrict__ x, const int* __restrict__ row_start,
                           const int2* __restrict__ epack, const float* __restrict__ dinv,
                           float* __restrict__ xagg) {
    int node = (blockIdx.x * blockDim.x + threadIdx.x) >> 6;
    int f = threadIdx.x & 63;
    if (node >= N_NODES) return;
    int beg = __builtin_amdgcn_readfirstlane(row_start[node]);
    int end = __builtin_amdgcn_readfirstlane(row_start[node + 1]);
    bool act = (f < F_IN);
    float sum = 0.0f;
    int j = beg;
    for (; j + 8 <= end; j += 8) {
        int2 p0 = epack[j+0]; int2 p1 = epack[j+1];
        int2 p2 = epack[j+2]; int2 p3 = epack[j+3];
        int2 p4 = epack[j+4]; int2 p5 = epack[j+5];
        int2 p6 = epack[j+6]; int2 p7 = epack[j+7];
        if (act) {
            float v0 = x[p0.x * F_IN + f], v1 = x[p1.x * F_IN + f];
            float v2 = x[p2.x * F_IN + f], v3 = x[p3.x * F_IN + f];
            float v4 = x[p4.x * F_IN + f], v5 = x[p5.x * F_IN + f];
            float v6 = x[p6.x * F_IN + f], v7 = x[p7.x * F_IN + f];
            sum += v0 * __int_as_float(p0.y) + v1 * __int_as_float(p1.y)
                 + v2 * __int_as_float(p2.y) + v3 * __int_as_float(p3.y)
                 + v4 * __int_as_float(p4.y) + v5 * __int_as_float(p5.y)
                 + v6 * __int_as_float(p6.y) + v7 * __int_as_float(p7.y);
        }
    }
    for (; j < end; ++j) {
        int2 p = epack[j];
        if (act) sum += x[p.x * F_IN + f] * __int_as_float(p.y);
    }
    if (act) {
        float dv = dinv[node];
        sum += x[node * F_IN + f] * dv * dv;
        xagg[node * F_IN + f] = sum;
    }
}

// ---- layer-1 matmul fused with bias+relu: out = relu(xagg @ W + b) ----
__global__ void k_mm_br(const float* __restrict__ xagg, const float* __restrict__ W,
                        const float* __restrict__ b, float* __restrict__ out) {
    __shared__ float sW[F_IN * HID];
    for (int i = threadIdx.x; i < F_IN * HID; i += blockDim.x) sW[i] = W[i];
    __syncthreads();
    int gid = blockIdx.x * blockDim.x + threadIdx.x;
    int node = gid >> 6;
    int f = gid & 63;
    if (node >= N_NODES) return;
    float s = b[f];
#pragma unroll
    for (int k = 0; k < F_IN; ++k) s += xagg[node * F_IN + k] * sW[k * HID + f];
    out[node * HID + f] = fmaxf(s, 0.0f);
}

// ---- h = x @ W : W column in VGPRs, x broadcast via v_readlane, no LDS ----
__device__ __forceinline__ float bcast(float v, int lane) {
    return __int_as_float(__builtin_amdgcn_readlane(__float_as_int(v), lane));
}

#define MM_BLOCKS 625    // 625 blocks * 4 waves = 2500 waves; 50000/2500 = 20 nodes/wave
__global__ void k_mm(const float* __restrict__ x, const float* __restrict__ W,
                     float* __restrict__ h) {
    int f = threadIdx.x & 63;
    // W column f -> 64 registers (coalesced loads across lanes per k)
    float wk[HID];
#pragma unroll
    for (int k = 0; k < HID; ++k) wk[k] = W[k * HID + f];
    int wv = blockIdx.x * (blockDim.x >> 6) + (threadIdx.x >> 6);
    const int nwaves = MM_BLOCKS * 4;
    for (int node = wv; node < N_NODES; node += nwaves) {
        float xv = x[node * HID + f];    // lane f holds x[node][f]
        float a0 = 0.0f, a1 = 0.0f, a2 = 0.0f, a3 = 0.0f;
#pragma unroll
        for (int k = 0; k < HID; k += 4) {
            a0 = fmaf(bcast(xv, k + 0), wk[k + 0], a0);
            a1 = fmaf(bcast(xv, k + 1), wk[k + 1], a1);
            a2 = fmaf(bcast(xv, k + 2), wk[k + 2], a2);
            a3 = fmaf(bcast(xv, k + 3), wk[k + 3], a3);
        }
        h[node * HID + f] = (a0 + a1) + (a2 + a3);
    }
}

// ---- per-node gather (64 features), 8x unrolled for ILP ----
__global__ void k_gather(const float* __restrict__ h, const int* __restrict__ row_start,
                         const int2* __restrict__ epack, const float* __restrict__ dinv,
                         const float* __restrict__ b, float* __restrict__ out) {
    int node = (blockIdx.x * blockDim.x + threadIdx.x) >> 6;
    int f = threadIdx.x & 63;
    if (node >= N_NODES) return;
    int beg = __builtin_amdgcn_readfirstlane(row_start[node]);
    int end = __builtin_amdgcn_readfirstlane(row_start[node + 1]);
    float sum = 0.0f;
    int j = beg;
    for (; j + 8 <= end; j += 8) {
        int2 p0 = epack[j+0]; int2 p1 = epack[j+1];
        int2 p2 = epack[j+2]; int2 p3 = epack[j+3];
        int2 p4 = epack[j+4]; int2 p5 = epack[j+5];
        int2 p6 = epack[j+6]; int2 p7 = epack[j+7];
        float v0 = h[p0.x * HID + f], v1 = h[p1.x * HID + f];
        float v2 = h[p2.x * HID + f], v3 = h[p3.x * HID + f];
        float v4 = h[p4.x * HID + f], v5 = h[p5.x * HID + f];
        float v6 = h[p6.x * HID + f], v7 = h[p7.x * HID + f];
        sum += v0 * __int_as_float(p0.y) + v1 * __int_as_float(p1.y)
             + v2 * __int_as_float(p2.y) + v3 * __int_as_float(p3.y)
             + v4 * __int_as_float(p4.y) + v5 * __int_as_float(p5.y)
             + v6 * __int_as_float(p6.y) + v7 * __int_as_float(p7.y);
    }
    for (; j < end; ++j) {
        int2 p = epack[j];
        sum += h[p.x * HID + f] * __int_as_float(p.y);
    }
    float dv = dinv[node];
    sum += h[node * HID + f] * dv * dv;
    out[node * HID + f] = fmaxf(sum + b[f], 0.0f);
}

// ---- segment sum for global mean pool (batch sorted; register partials) ----
#define POOL_BLOCKS 200
__global__ void k_pool(const float* __restrict__ x, const int* __restrict__ batch,
                       float* __restrict__ gsum, float* __restrict__ gcnt) {
    const int npb = (N_NODES + POOL_BLOCKS - 1) / POOL_BLOCKS;   // 250
    int start = blockIdx.x * npb;
    int end = start + npb;
    if (end > N_NODES) end = N_NODES;
    int f = threadIdx.x & 63;
    int grp = threadIdx.x >> 6;       // 0..3 (4 waves)
    float sum = 0.0f, cnt = 0.0f;
    int curg = -1;
    for (int node = start + grp; node < end; node += 4) {
        int g = batch[node];
        if (g != curg) {
            if (curg >= 0) {
                atomicAdd(&gsum[curg * HID + f], sum);
                if (f == 0) atomicAdd(&gcnt[curg], cnt);
            }
            curg = g; sum = 0.0f; cnt = 0.0f;
        }
        sum += x[node * HID + f];
        cnt += 1.0f;
    }
    if (curg >= 0) {
        atomicAdd(&gsum[curg * HID + f], sum);
        if (f == 0) atomicAdd(&gcnt[curg], cnt);
    }
}

// ---- final FC: out = relu((gsum/cnt) @ Wfc + bfc) ----
__global__ void k_fc(const float* __restrict__ gsum, const float* __restrict__ gcnt,
                     const float* __restrict__ Wfc, const float* __restrict__ bfc,
                     float* __restrict__ out) {
    int gid = blockIdx.x * blockDim.x + threadIdx.x;   // 64*128 threads
    if (gid >= N_GRAPHS * EMB) return;
    int g = gid >> 7;
    int j = gid & 127;
    float inv = 1.0f / fmaxf(gcnt[g], 1.0f);
    float s = bfc[j];
#pragma unroll 8
    for (int k = 0; k < HID; ++k) s += gsum[g * HID + k] * inv * Wfc[k * EMB + j];
    out[gid] = fmaxf(s, 0.0f);
}

extern "C" void kernel_launch(void* const* d_in, const int* in_sizes, int n_in,
                              void* d_out, int out_size, void* d_ws, size_t ws_size,
                              hipStream_t stream) {
    const float* x    = (const float*)d_in[0];
    const int*   ei   = (const int*)d_in[1];
    const int*   batch= (const int*)d_in[2];
    const float* W1   = (const float*)d_in[3];
    const float* b1   = (const float*)d_in[4];
    const float* W2   = (const float*)d_in[5];
    const float* b2   = (const float*)d_in[6];
    const float* W3   = (const float*)d_in[7];
    const float* b3   = (const float*)d_in[8];
    const float* Wfc  = (const float*)d_in[9];
    const float* bfc  = (const float*)d_in[10];
    float* out = (float*)d_out;

    // workspace layout (4-byte words)
    float* ws        = (float*)d_ws;
    float* dinv      = ws;                                 // 50048
    float* h         = ws + 50048;                         // 3.2M (also xagg in layer 1)
    float* xcur      = h + N_NODES * HID;                  // 3.2M
    float* gsum      = xcur + N_NODES * HID;               // 4096
    float* gcnt      = gsum + N_GRAPHS * HID;              // 64
    int*   ecnt      = (int*)(gcnt + 64);                  // 50048
    int*   row_start = ecnt + 50048;                       // 50056
    int*   pos       = row_start + 50056;                  // 50048
    int*   bsum      = pos + 50048;                        // 256
    int*   boff      = bsum + 256;                         // 256
    int2*  epack     = (int2*)(boff + 256);                // 800000 int2 (8B aligned)
    float* xagg      = h;                                  // [N, F_IN] reuse (h dead in layer 1)

    const int* src = ei;                       // edge_index[0]
    const int* dst = ei + N_EDGES;             // edge_index[1]

    const int B = 256;
    const int gN   = (N_NODES + B - 1) / B;
    const int gE   = (N_EDGES + B - 1) / B;
    const int gNF  = (N_NODES * HID + B - 1) / B;

    // CSR build
    k_init<<<gN, B, 0, stream>>>(ecnt, gsum, gcnt);
    k_hist<<<gE, B, 0, stream>>>(dst, ecnt);
    k_sum<<<NB_SCAN, SCAN_B, 0, stream>>>(ecnt, bsum);
    k_bscan<<<1, SCAN_B, 0, stream>>>(bsum, boff, row_start);
    k_scan3<<<NB_SCAN, SCAN_B, 0, stream>>>(ecnt, boff, row_start, pos, dinv);
    k_bucket<<<gE, B, 0, stream>>>(src, dst, dinv, row_start, pos, epack);

    // layer 1: aggregate-then-transform (X is only 6-wide)
    k_gather_x<<<gNF, B, 0, stream>>>(x, row_start, epack, dinv, xagg);
    k_mm_br<<<gNF, B, 0, stream>>>(xagg, W1, b1, xcur);
    // layer 2
    k_mm<<<MM_BLOCKS, B, 0, stream>>>(xcur, W2, h);
    k_gather<<<gNF, B, 0, stream>>>(h, row_start, epack, dinv, b2, xcur);
    // layer 3
    k_mm<<<MM_BLOCKS, B, 0, stream>>>(xcur, W3, h);
    k_gather<<<gNF, B, 0, stream>>>(h, row_start, epack, dinv, b3, xcur);

    // pool + FC
    k_pool<<<POOL_BLOCKS, B, 0, stream>>>(xcur, batch, gsum, gcnt);
    k_fc<<<(N_GRAPHS * EMB + B - 1) / B, B, 0, stream>>>(gsum, gcnt, Wfc, bfc, out);
}